// Round 9
// baseline (93.920 us; speedup 1.0000x reference)
//
#include <hip/hip_runtime.h>
#include <hip/hip_bf16.h>

// ---------------------------------------------------------------------------
// MultiHeadAttention: feats L2-norm + clamp(coords) concat -> per-head QKV
// (DIN=259, HD=32, H=8) -> softmax attention (N=4096, clip +-100, /(sum+1e-6))
// -> output proj + bias + residual.
// Precision: hi/lo bf16 split (3-MFMA fp32 emulation) for QKV proj and QK^T;
// bf16 P and bf16 V for PV; plain bf16 for output proj.
// Attention: swapped-operand QK^T (S^T = K.Q^T, log2 domain via pre-scaled Q),
// fixed-scale softmax p' = 2^(s-64) folded into the MFMA C-init (no clip:
// score bound 98 log2-units << 144; reference's clip at 100 equally inert),
// row-sums via ones-MFMA (matrix pipe, no VALU adds, no shuffles),
// split-K 8 waves/block (512 thr) on a 32-row Q-tile; LDS sum-combine.
// ---------------------------------------------------------------------------

using s8  = __attribute__((ext_vector_type(8))) short;   // 8 x bf16 (4 VGPR)
using s4v = __attribute__((ext_vector_type(4))) short;   // 4 x bf16 (2 VGPR)
using f4  = __attribute__((ext_vector_type(4))) float;   // MFMA C/D
typedef unsigned short u16;
typedef unsigned int   u32;

#define NPTS 4096
#define NH   8
#define HD   32
#define DIN  259
#define DINP 288       // padded K-dim for QKV GEMM (9 x 32)
#define COUT 768       // 3*NH*HD, col c = s*256 + h*32 + hd (s: 0=q,1=k,2=v)
#define KBLK 64        // attention keys per inner iteration
#define KSPLIT 8       // waves per block, each takes NPTS/KSPLIT keys
#define QROWS 32       // q-rows per block (two 16-row MFMA tiles)

// scale * log2(e): QK^T in log2 domain (monotone, identical softmax)
#define SCL2  (0.17677669529663687f * 1.4426950408889634f)
#define PRESC 64.0f    // fixed softmax prescale: p' = 2^(s - 64)

#define MFMA32(a, b, c) __builtin_amdgcn_mfma_f32_16x16x32_bf16((a), (b), (c), 0, 0, 0)

#if __has_builtin(__builtin_amdgcn_mfma_f32_16x16x16bf16_1k)
#define HAVE_MFMA16 1
#define MFMA16(a, b, c) __builtin_amdgcn_mfma_f32_16x16x16bf16_1k((a), (b), (c), 0, 0, 0)
#else
#define HAVE_MFMA16 0
#endif

#if __has_builtin(__builtin_amdgcn_exp2f)
#define EXP2(x) __builtin_amdgcn_exp2f(x)
#else
#define EXP2(x) exp2f(x)
#endif

__device__ __forceinline__ u16 f2bf(float f) {           // RNE, for cold paths
    u32 u = __float_as_uint(f);
    u32 r = u + 0x7FFFu + ((u >> 16) & 1u);
    return (u16)(r >> 16);
}
__device__ __forceinline__ float bf2f(u16 h) { return __uint_as_float(((u32)h) << 16); }
__device__ __forceinline__ void splitbf(float v, u16& hi, u16& lo) {
    hi = f2bf(v);
    lo = f2bf(v - bf2f(hi));
}
__device__ __forceinline__ u16 cvt1(float f) {           // native convert (RNE)
    __hip_bfloat16 b = __float2bfloat16(f);
    return *reinterpret_cast<u16*>(&b);
}
__device__ __forceinline__ s8 ld8(const u16* p) { return *reinterpret_cast<const s8*>(p); }
__device__ __forceinline__ u32 bfpair(float a, float b) {
    return (u32)cvt1(a) | ((u32)cvt1(b) << 16);
}

// ---------------------------------------------------------------------------
// Phase 0a: build transposed+split QKV weight matrix Wt[COUT][DINP]
// ---------------------------------------------------------------------------
__global__ void k_wprep(const float* __restrict__ wq, const float* __restrict__ wk,
                        const float* __restrict__ wv,
                        u16* __restrict__ wtHi, u16* __restrict__ wtLo) {
    int c = blockIdx.x;                   // 0..767
    int s = c >> 8, h = (c >> 5) & 7, hd = c & 31;
    const float* w = (s == 0) ? wq : (s == 1) ? wk : wv;
    for (int k = threadIdx.x; k < DINP; k += blockDim.x) {
        float val = (k < DIN) ? w[(h * DIN + k) * HD + hd] : 0.0f;
        u16 hi, lo; splitbf(val, hi, lo);
        wtHi[c * DINP + k] = hi;
        wtLo[c * DINP + k] = lo;
    }
}

// ---------------------------------------------------------------------------
// Phase 0b: woT[c][k] = wo[k][c] (bf16)
// ---------------------------------------------------------------------------
__global__ void k_woprep(const float* __restrict__ wo, u16* __restrict__ woT) {
    int c = blockIdx.x;
    int k = threadIdx.x;                  // blockDim = 256
    woT[c * 256 + k] = f2bf(wo[k * 256 + c]);
}

// ---------------------------------------------------------------------------
// Phase 1: featurize. One 64-lane wave per row.
// ---------------------------------------------------------------------------
__global__ __launch_bounds__(64) void k_featurize(const float* __restrict__ x,
                                                  const int* __restrict__ coords,
                                                  u16* __restrict__ xcHi,
                                                  u16* __restrict__ xcLo) {
    int row = blockIdx.x;
    int l = threadIdx.x;
    f4 v = *reinterpret_cast<const f4*>(x + row * 256 + 4 * l);
    float ss = v[0] * v[0] + v[1] * v[1] + v[2] * v[2] + v[3] * v[3];
#pragma unroll
    for (int m = 1; m < 64; m <<= 1) ss += __shfl_xor(ss, m);
    float inv = 1.0f / (sqrtf(ss) + 1e-6f);
#pragma unroll
    for (int j = 0; j < 4; ++j) {
        u16 hi, lo; splitbf(v[j] * inv, hi, lo);
        xcHi[row * DINP + 4 * l + j] = hi;
        xcLo[row * DINP + 4 * l + j] = lo;
    }
    if (l < 32) {
        int col = 256 + l;
        float val = 0.0f;
        if (col < DIN) {
            float c = (float)coords[row * 3 + (col - 256)];
            val = fminf(fmaxf(c, -100.0f), 100.0f);
        }
        u16 hi, lo; splitbf(val, hi, lo);
        xcHi[row * DINP + col] = hi;
        xcLo[row * DINP + col] = lo;
    }
}

// ---------------------------------------------------------------------------
// Phase 2: QKV GEMM  [4096 x DINP] x [DINP x 768] with 3-MFMA emulation.
// q (pre-scaled by SCL2), k row-major [h][n][hd] (hi/lo);
// v tiled [h][n>>4][hd][n&15] (bf16).
// ---------------------------------------------------------------------------
__global__ __launch_bounds__(256) void k_qkv(
        const u16* __restrict__ xcHi, const u16* __restrict__ xcLo,
        const u16* __restrict__ wtHi, const u16* __restrict__ wtLo,
        const float* __restrict__ bq, const float* __restrict__ bk,
        const float* __restrict__ bv,
        u16* __restrict__ qHi, u16* __restrict__ qLo,
        u16* __restrict__ kHi, u16* __restrict__ kLo,
        u16* __restrict__ vt2) {
    int w = threadIdx.x >> 6, l = threadIdx.x & 63;
    int lr = l & 15, lg = l >> 4;
    int r0 = blockIdx.x * 64 + w * 16;    // wave's row base
    int c0 = blockIdx.y * 64;             // block's col base

    f4 acc[4] = {};
    const u16* aH = xcHi + (r0 + lr) * DINP + lg * 8;
    const u16* aL = xcLo + (r0 + lr) * DINP + lg * 8;
#pragma unroll
    for (int kk = 0; kk < 9; ++kk) {
        s8 ah = ld8(aH + kk * 32);
        s8 al = ld8(aL + kk * 32);
#pragma unroll
        for (int ct = 0; ct < 4; ++ct) {
            int c = c0 + ct * 16 + lr;
            s8 bh = ld8(wtHi + c * DINP + kk * 32 + lg * 8);
            s8 bl = ld8(wtLo + c * DINP + kk * 32 + lg * 8);
            acc[ct] = MFMA32(al, bh, acc[ct]);
            acc[ct] = MFMA32(ah, bl, acc[ct]);
            acc[ct] = MFMA32(ah, bh, acc[ct]);
        }
    }
#pragma unroll
    for (int ct = 0; ct < 4; ++ct) {
        int c = c0 + ct * 16 + lr;
        int s = c >> 8, h = (c >> 5) & 7, hd = c & 31;
        float bias = ((s == 0) ? bq : (s == 1) ? bk : bv)[h * HD + hd];
#pragma unroll
        for (int r = 0; r < 4; ++r) {
            int n = r0 + lg * 4 + r;
            float val = acc[ct][r] + bias;
            if (s == 0) {
                u16 hi, lo; splitbf(val * SCL2, hi, lo);   // pre-scaled Q
                qHi[(h * NPTS + n) * HD + hd] = hi;
                qLo[(h * NPTS + n) * HD + hd] = lo;
            } else if (s == 1) {
                u16 hi, lo; splitbf(val, hi, lo);
                kHi[(h * NPTS + n) * HD + hd] = hi;
                kLo[(h * NPTS + n) * HD + hd] = lo;
            } else {
                // tiled V^T: [h][key tile][hd][key%16]
                vt2[((size_t)(h * 256 + (n >> 4)) * 32 + hd) * 16 + (n & 15)] = f2bf(val);
            }
        }
    }
}

// ---------------------------------------------------------------------------
// Phase 3: attention. 512-thread blocks = 8 waves on one (head, 32 q-rows);
// wave w handles keys [w*512, (w+1)*512) in 8 iters of 64 keys. Fixed-scale
// softmax: C-init = -64 folds the prescale into QK^T; no clip (score bound
// 98 log2 < 144). Row-sums S' via ones-MFMA (all lanes get S, zero VALU).
// Two 16-row score tiles share all K/V fragments. LDS sum-combine, wave 0
// writes. blockIdx&7 = head -> per-XCD L2 holds one head's K/V.
// ---------------------------------------------------------------------------
__global__ __launch_bounds__(512, 4) void k_attn(
        const u16* __restrict__ qHi, const u16* __restrict__ qLo,
        const u16* __restrict__ kHi, const u16* __restrict__ kLo,
        const u16* __restrict__ vt2,
        u16* __restrict__ catH) {
    __shared__ float cmb[KSPLIT][64][19];  // {SA,o0A[4],o1A[4],SB,o0B[4],o1B[4]}
    int b = blockIdx.x;
    int h = b & 7;                        // head -> XCD affinity
    int qb = b >> 3;                      // 0..127 (32 rows each)
    int w = threadIdx.x >> 6;             // key-split index 0..7
    int l = threadIdx.x & 63, lr = l & 15, lg = l >> 4;

    size_t qoff = (size_t)(h * NPTS + qb * QROWS + lr) * HD + lg * 8;
    s8 qh0 = ld8(qHi + qoff);
    s8 ql0 = ld8(qLo + qoff);
    s8 qh1 = ld8(qHi + qoff + 16 * HD);
    s8 ql1 = ld8(qLo + qoff + 16 * HD);

    // hoisted bases (32-bit per-iter offsets)
    const u16* khb = kHi + (size_t)h * NPTS * HD + lr * HD + lg * 8;
    const u16* klb = kLo + (size_t)h * NPTS * HD + lr * HD + lg * 8;
    const u16* vtb = vt2 + (size_t)h * (NPTS / 16) * 512 + lr * 16 + lg * 4;

    const f4 cinit = {-PRESC, -PRESC, -PRESC, -PRESC};
    const s4v vones = {(short)0x3F80, (short)0x3F80, (short)0x3F80, (short)0x3F80};

    f4 o0A = {}, o1A = {}, o0B = {}, o1B = {};
    f4 oSA = {}, oSB = {};                 // ones-MFMA row sums (all lanes = S)

#pragma unroll 1
    for (int kb = w * (NPTS / KSPLIT / KBLK); kb < (w + 1) * (NPTS / KSPLIT / KBLK); ++kb) {
        // S^T tiles: st*[kt] holds s'-64 for [key = kt*16+lg*4+r][q = lr]
        f4 stA[4], stB[4];
#pragma unroll
        for (int kt = 0; kt < 4; ++kt) {
            int koff = (kb * KBLK + kt * 16) * HD;
            s8 kh = ld8(khb + koff);
            s8 kl = ld8(klb + koff);
            f4 a = MFMA32(kl, qh0, cinit);
            a = MFMA32(kh, ql0, a);
            a = MFMA32(kh, qh0, a);
            stA[kt] = a;
            f4 bb = MFMA32(kl, qh1, cinit);
            bb = MFMA32(kh, ql1, bb);
            bb = MFMA32(kh, qh1, bb);
            stB[kt] = bb;
        }
        // p' = 2^(s-64); pack to bf16 (no clip, no sub, no scalar sums)
        u32 pkA0[4], pkA1[4], pkB0[4], pkB1[4];
#pragma unroll
        for (int kt = 0; kt < 4; ++kt) {
            float a0 = EXP2(stA[kt][0]);
            float a1 = EXP2(stA[kt][1]);
            float a2 = EXP2(stA[kt][2]);
            float a3 = EXP2(stA[kt][3]);
            pkA0[kt] = bfpair(a0, a1);
            pkA1[kt] = bfpair(a2, a3);
            float b0 = EXP2(stB[kt][0]);
            float b1 = EXP2(stB[kt][1]);
            float b2 = EXP2(stB[kt][2]);
            float b3 = EXP2(stB[kt][3]);
            pkB0[kt] = bfpair(b0, b1);
            pkB1[kt] = bfpair(b2, b3);
        }

        // PV: O'^T += V^T . P'^T ; S' += ones . P'^T (matrix pipe)
        int vo = kb * 2048;
#if HAVE_MFMA16
#pragma unroll
        for (int kt = 0; kt < 4; ++kt) {
            union { u32 u[2]; s4v v; } puA, puB;
            puA.u[0] = pkA0[kt]; puA.u[1] = pkA1[kt];
            puB.u[0] = pkB0[kt]; puB.u[1] = pkB1[kt];
            s4v v0 = *reinterpret_cast<const s4v*>(vtb + vo + kt * 512);
            s4v v1 = *reinterpret_cast<const s4v*>(vtb + vo + kt * 512 + 256);
            o0A = MFMA16(v0, puA.v, o0A);
            o1A = MFMA16(v1, puA.v, o1A);
            oSA = MFMA16(vones, puA.v, oSA);
            o0B = MFMA16(v0, puB.v, o0B);
            o1B = MFMA16(v1, puB.v, o1B);
            oSB = MFMA16(vones, puB.v, oSB);
        }
#else
        // fallback: assemble 16x16x32 B-frags via shuffles (per q-tile)
        int srcbase = ((lg & 1) * 2) * 16 + lr;
        bool hiQuad = (lg >> 1) != 0;
#pragma unroll
        for (int s = 0; s < 2; ++s) {
            union { u32 u[4]; s8 v; } buA, buB;
#pragma unroll
            for (int wi = 0; wi < 4; ++wi) {
                int src = srcbase + ((wi >> 1) << 4);
                u32 a0 = (u32)__shfl((int)((wi & 1) ? pkA1[2 * s] : pkA0[2 * s]), src);
                u32 a1 = (u32)__shfl((int)((wi & 1) ? pkA1[2 * s + 1] : pkA0[2 * s + 1]), src);
                buA.u[wi] = hiQuad ? a1 : a0;
                u32 b0 = (u32)__shfl((int)((wi & 1) ? pkB1[2 * s] : pkB0[2 * s]), src);
                u32 b1 = (u32)__shfl((int)((wi & 1) ? pkB1[2 * s + 1] : pkB0[2 * s + 1]), src);
                buB.u[wi] = hiQuad ? b1 : b0;
            }
            int t = 2 * s + (lg >> 1);
            const u16* vt = vtb - lr * 16 - lg * 4 + vo + t * 512 + (lg & 1) * 8;
            s8 v0 = ld8(vt + lr * 16);
            s8 v1 = ld8(vt + (16 + lr) * 16);
            union { u32 u[4]; s8 v; } onesu;
            onesu.u[0] = onesu.u[1] = onesu.u[2] = onesu.u[3] = 0x3F803F80u;
            o0A = MFMA32(v0, buA.v, o0A);
            o1A = MFMA32(v1, buA.v, o1A);
            oSA = MFMA32(onesu.v, buA.v, oSA);
            o0B = MFMA32(v0, buB.v, o0B);
            o1B = MFMA32(v1, buB.v, o1B);
            oSB = MFMA32(onesu.v, buB.v, oSB);
        }
#endif
    }

    // deposit per-wave partials (all share the fixed 2^-64 scale);
    // every lane of oS* holds the full per-q row sum already.
    float* c = cmb[w][l];
    c[0] = oSA[0];
#pragma unroll
    for (int r = 0; r < 4; ++r) { c[1 + r] = o0A[r]; c[5 + r] = o1A[r]; }
    c[9] = oSB[0];
#pragma unroll
    for (int r = 0; r < 4; ++r) { c[10 + r] = o0B[r]; c[14 + r] = o1B[r]; }
    __syncthreads();

    if (w == 0) {
        float StA = 0.0f, StB = 0.0f;
        f4 O0A = {}, O1A = {}, O0B = {}, O1B = {};
#pragma unroll
        for (int ww = 0; ww < KSPLIT; ++ww) {
            const float* cc = cmb[ww][l];
            StA += cc[0];
            StB += cc[9];
#pragma unroll
            for (int r = 0; r < 4; ++r) {
                O0A[r] += cc[1 + r];
                O1A[r] += cc[5 + r];
                O0B[r] += cc[10 + r];
                O1B[r] += cc[14 + r];
            }
        }
        // reference's +1e-6 on the max-normalized sum perturbs output by
        // <=1e-6 relative -- negligible vs bf16 rounding; plain divide.
        float invA = 1.0f / StA;
        float invB = 1.0f / StB;
        int n = qb * QROWS + lr;
        u16* dstA = catH + n * 256 + h * HD + lg * 4;
        *reinterpret_cast<uint2*>(dstA) =
            make_uint2(bfpair(O0A[0] * invA, O0A[1] * invA),
                       bfpair(O0A[2] * invA, O0A[3] * invA));
        *reinterpret_cast<uint2*>(dstA + 16) =
            make_uint2(bfpair(O1A[0] * invA, O1A[1] * invA),
                       bfpair(O1A[2] * invA, O1A[3] * invA));
        u16* dstB = dstA + 16 * 256;
        *reinterpret_cast<uint2*>(dstB) =
            make_uint2(bfpair(O0B[0] * invB, O0B[1] * invB),
                       bfpair(O0B[2] * invB, O0B[3] * invB));
        *reinterpret_cast<uint2*>(dstB + 16) =
            make_uint2(bfpair(O1B[0] * invB, O1B[1] * invB),
                       bfpair(O1B[2] * invB, O1B[3] * invB));
    }
}

// ---------------------------------------------------------------------------
// Phase 4: out = cat @ wo + bo + x   (bf16 MFMA, fp32 epilogue)
// ---------------------------------------------------------------------------
__global__ __launch_bounds__(256) void k_out(
        const u16* __restrict__ catH, const u16* __restrict__ woT,
        const float* __restrict__ bo, const float* __restrict__ x,
        float* __restrict__ out) {
    int w = threadIdx.x >> 6, l = threadIdx.x & 63;
    int lr = l & 15, lg = l >> 4;
    int r0 = blockIdx.x * 64 + w * 16;
    int c0 = blockIdx.y * 64;
    f4 acc[4] = {};
#pragma unroll
    for (int kk = 0; kk < 8; ++kk) {
        s8 a = ld8(catH + (r0 + lr) * 256 + kk * 32 + lg * 8);
#pragma unroll
        for (int ct = 0; ct < 4; ++ct) {
            s8 b = ld8(woT + (c0 + ct * 16 + lr) * 256 + kk * 32 + lg * 8);
            acc[ct] = MFMA32(a, b, acc[ct]);
        }
    }
#pragma unroll
    for (int ct = 0; ct < 4; ++ct) {
        int c = c0 + ct * 16 + lr;
        float bias = bo[c];
#pragma unroll
        for (int r = 0; r < 4; ++r) {
            int n = r0 + lg * 4 + r;
            out[n * 256 + c] = acc[ct][r] + bias + x[n * 256 + c];
        }
    }
}

// ---------------------------------------------------------------------------
extern "C" void kernel_launch(void* const* d_in, const int* in_sizes, int n_in,
                              void* d_out, int out_size, void* d_ws, size_t ws_size,
                              hipStream_t stream) {
    const float* x      = (const float*)d_in[0];
    const int*   coords = (const int*)d_in[1];
    const float* wq     = (const float*)d_in[2];
    const float* bq     = (const float*)d_in[3];
    const float* wk     = (const float*)d_in[4];
    const float* bk     = (const float*)d_in[5];
    const float* wv     = (const float*)d_in[6];
    const float* bv     = (const float*)d_in[7];
    const float* wo     = (const float*)d_in[8];
    const float* bo     = (const float*)d_in[9];
    float* out = (float*)d_out;

    char* ws = (char*)d_ws;
    size_t off = 0;
    auto alloc = [&](size_t bytes) {
        char* p = ws + off;
        off = (off + bytes + 255) & ~(size_t)255;
        return p;
    };
    u16* xcHi = (u16*)alloc((size_t)NPTS * DINP * 2);
    u16* xcLo = (u16*)alloc((size_t)NPTS * DINP * 2);
    u16* wtHi = (u16*)alloc((size_t)COUT * DINP * 2);
    u16* wtLo = (u16*)alloc((size_t)COUT * DINP * 2);
    u16* qHi  = (u16*)alloc((size_t)NH * NPTS * HD * 2);
    u16* qLo  = (u16*)alloc((size_t)NH * NPTS * HD * 2);
    u16* kHi  = (u16*)alloc((size_t)NH * NPTS * HD * 2);
    u16* kLo  = (u16*)alloc((size_t)NH * NPTS * HD * 2);
    u16* vt2  = (u16*)alloc((size_t)NH * NPTS * HD * 2);
    u16* catH = (u16*)alloc((size_t)NPTS * 256 * 2);
    u16* woT  = (u16*)alloc((size_t)256 * 256 * 2);
    (void)ws_size; (void)in_sizes; (void)n_in; (void)out_size;

    k_wprep<<<COUT, 64, 0, stream>>>(wq, wk, wv, wtHi, wtLo);
    k_woprep<<<256, 256, 0, stream>>>(wo, woT);
    k_featurize<<<NPTS, 64, 0, stream>>>(x, coords, xcHi, xcLo);
    k_qkv<<<dim3(NPTS / 64, COUT / 64), 256, 0, stream>>>(
        xcHi, xcLo, wtHi, wtLo, bq, bk, bv, qHi, qLo, kHi, kLo, vt2);
    k_attn<<<NPTS / QROWS * NH, 512, 0, stream>>>(qHi, qLo, kHi, kLo, vt2, catH);
    k_out<<<dim3(NPTS / 64, 256 / 64), 256, 0, stream>>>(catH, woT, bo, x, out);
}

// Round 10
// 93.858 us; speedup vs baseline: 1.0007x; 1.0007x over previous
//
#include <hip/hip_runtime.h>
#include <hip/hip_bf16.h>

// ---------------------------------------------------------------------------
// MultiHeadAttention: feats L2-norm + clamp(coords) concat -> per-head QKV
// (DIN=259, HD=32, H=8) -> softmax attention (N=4096, clip +-100, /(sum+1e-6))
// -> output proj + bias + residual.
// Precision: hi/lo bf16 split (3-MFMA fp32 emulation) for QKV proj and QK^T;
// bf16 P and bf16 V for PV; plain bf16 for output proj.
// Attention: swapped-operand QK^T (S^T = K.Q^T, log2 domain via pre-scaled Q),
// fixed-scale softmax p' = 2^(s-64) folded into the MFMA C-init (no clip:
// score bound 98 log2-units << 144; reference's clip at 100 equally inert).
// Inner loop = independent 16-key granules with a tiny live set, unroll 2 so
// the compiler software-pipelines K/V loads under MFMA+exp2 (round-9 lesson:
// both pipes at 34%, stall-bound). Row sums on VALU (2 chains/tile).
// Split-K 8 waves/block (512 thr) on a 32-row Q-tile; LDS sum-combine.
// ---------------------------------------------------------------------------

using s8  = __attribute__((ext_vector_type(8))) short;   // 8 x bf16 (4 VGPR)
using s4v = __attribute__((ext_vector_type(4))) short;   // 4 x bf16 (2 VGPR)
using f4  = __attribute__((ext_vector_type(4))) float;   // MFMA C/D
typedef unsigned short u16;
typedef unsigned int   u32;

#define NPTS 4096
#define NH   8
#define HD   32
#define DIN  259
#define DINP 288       // padded K-dim for QKV GEMM (9 x 32)
#define COUT 768       // 3*NH*HD, col c = s*256 + h*32 + hd (s: 0=q,1=k,2=v)
#define KSPLIT 8       // waves per block, each takes NPTS/KSPLIT keys
#define QROWS 32       // q-rows per block (two 16-row MFMA tiles)
#define KTPW (NPTS / KSPLIT / 16)   // 16-key granules per wave = 32

// scale * log2(e): QK^T in log2 domain (monotone, identical softmax)
#define SCL2  (0.17677669529663687f * 1.4426950408889634f)
#define PRESC 64.0f    // fixed softmax prescale: p' = 2^(s - 64)

#define MFMA32(a, b, c) __builtin_amdgcn_mfma_f32_16x16x32_bf16((a), (b), (c), 0, 0, 0)

#if __has_builtin(__builtin_amdgcn_mfma_f32_16x16x16bf16_1k)
#define HAVE_MFMA16 1
#define MFMA16(a, b, c) __builtin_amdgcn_mfma_f32_16x16x16bf16_1k((a), (b), (c), 0, 0, 0)
#else
#define HAVE_MFMA16 0
#endif

#if __has_builtin(__builtin_amdgcn_exp2f)
#define EXP2(x) __builtin_amdgcn_exp2f(x)
#else
#define EXP2(x) exp2f(x)
#endif

__device__ __forceinline__ u16 f2bf(float f) {           // RNE, for cold paths
    u32 u = __float_as_uint(f);
    u32 r = u + 0x7FFFu + ((u >> 16) & 1u);
    return (u16)(r >> 16);
}
__device__ __forceinline__ float bf2f(u16 h) { return __uint_as_float(((u32)h) << 16); }
__device__ __forceinline__ void splitbf(float v, u16& hi, u16& lo) {
    hi = f2bf(v);
    lo = f2bf(v - bf2f(hi));
}
__device__ __forceinline__ u16 cvt1(float f) {           // native convert (RNE)
    __hip_bfloat16 b = __float2bfloat16(f);
    return *reinterpret_cast<u16*>(&b);
}
__device__ __forceinline__ s8 ld8(const u16* p) { return *reinterpret_cast<const s8*>(p); }
__device__ __forceinline__ u32 bfpair(float a, float b) {
    return (u32)cvt1(a) | ((u32)cvt1(b) << 16);
}

// ---------------------------------------------------------------------------
// Phase 0a: build transposed+split QKV weight matrix Wt[COUT][DINP]
// ---------------------------------------------------------------------------
__global__ void k_wprep(const float* __restrict__ wq, const float* __restrict__ wk,
                        const float* __restrict__ wv,
                        u16* __restrict__ wtHi, u16* __restrict__ wtLo) {
    int c = blockIdx.x;                   // 0..767
    int s = c >> 8, h = (c >> 5) & 7, hd = c & 31;
    const float* w = (s == 0) ? wq : (s == 1) ? wk : wv;
    for (int k = threadIdx.x; k < DINP; k += blockDim.x) {
        float val = (k < DIN) ? w[(h * DIN + k) * HD + hd] : 0.0f;
        u16 hi, lo; splitbf(val, hi, lo);
        wtHi[c * DINP + k] = hi;
        wtLo[c * DINP + k] = lo;
    }
}

// ---------------------------------------------------------------------------
// Phase 0b: woT[c][k] = wo[k][c] (bf16)
// ---------------------------------------------------------------------------
__global__ void k_woprep(const float* __restrict__ wo, u16* __restrict__ woT) {
    int c = blockIdx.x;
    int k = threadIdx.x;                  // blockDim = 256
    woT[c * 256 + k] = f2bf(wo[k * 256 + c]);
}

// ---------------------------------------------------------------------------
// Phase 1: featurize. One 64-lane wave per row.
// ---------------------------------------------------------------------------
__global__ __launch_bounds__(64) void k_featurize(const float* __restrict__ x,
                                                  const int* __restrict__ coords,
                                                  u16* __restrict__ xcHi,
                                                  u16* __restrict__ xcLo) {
    int row = blockIdx.x;
    int l = threadIdx.x;
    f4 v = *reinterpret_cast<const f4*>(x + row * 256 + 4 * l);
    float ss = v[0] * v[0] + v[1] * v[1] + v[2] * v[2] + v[3] * v[3];
#pragma unroll
    for (int m = 1; m < 64; m <<= 1) ss += __shfl_xor(ss, m);
    float inv = 1.0f / (sqrtf(ss) + 1e-6f);
#pragma unroll
    for (int j = 0; j < 4; ++j) {
        u16 hi, lo; splitbf(v[j] * inv, hi, lo);
        xcHi[row * DINP + 4 * l + j] = hi;
        xcLo[row * DINP + 4 * l + j] = lo;
    }
    if (l < 32) {
        int col = 256 + l;
        float val = 0.0f;
        if (col < DIN) {
            float c = (float)coords[row * 3 + (col - 256)];
            val = fminf(fmaxf(c, -100.0f), 100.0f);
        }
        u16 hi, lo; splitbf(val, hi, lo);
        xcHi[row * DINP + col] = hi;
        xcLo[row * DINP + col] = lo;
    }
}

// ---------------------------------------------------------------------------
// Phase 2: QKV GEMM  [4096 x DINP] x [DINP x 768] with 3-MFMA emulation.
// q (pre-scaled by SCL2), k row-major [h][n][hd] (hi/lo);
// v tiled [h][n>>4][hd][n&15] (bf16).
// ---------------------------------------------------------------------------
__global__ __launch_bounds__(256) void k_qkv(
        const u16* __restrict__ xcHi, const u16* __restrict__ xcLo,
        const u16* __restrict__ wtHi, const u16* __restrict__ wtLo,
        const float* __restrict__ bq, const float* __restrict__ bk,
        const float* __restrict__ bv,
        u16* __restrict__ qHi, u16* __restrict__ qLo,
        u16* __restrict__ kHi, u16* __restrict__ kLo,
        u16* __restrict__ vt2) {
    int w = threadIdx.x >> 6, l = threadIdx.x & 63;
    int lr = l & 15, lg = l >> 4;
    int r0 = blockIdx.x * 64 + w * 16;    // wave's row base
    int c0 = blockIdx.y * 64;             // block's col base

    f4 acc[4] = {};
    const u16* aH = xcHi + (r0 + lr) * DINP + lg * 8;
    const u16* aL = xcLo + (r0 + lr) * DINP + lg * 8;
#pragma unroll
    for (int kk = 0; kk < 9; ++kk) {
        s8 ah = ld8(aH + kk * 32);
        s8 al = ld8(aL + kk * 32);
#pragma unroll
        for (int ct = 0; ct < 4; ++ct) {
            int c = c0 + ct * 16 + lr;
            s8 bh = ld8(wtHi + c * DINP + kk * 32 + lg * 8);
            s8 bl = ld8(wtLo + c * DINP + kk * 32 + lg * 8);
            acc[ct] = MFMA32(al, bh, acc[ct]);
            acc[ct] = MFMA32(ah, bl, acc[ct]);
            acc[ct] = MFMA32(ah, bh, acc[ct]);
        }
    }
#pragma unroll
    for (int ct = 0; ct < 4; ++ct) {
        int c = c0 + ct * 16 + lr;
        int s = c >> 8, h = (c >> 5) & 7, hd = c & 31;
        float bias = ((s == 0) ? bq : (s == 1) ? bk : bv)[h * HD + hd];
#pragma unroll
        for (int r = 0; r < 4; ++r) {
            int n = r0 + lg * 4 + r;
            float val = acc[ct][r] + bias;
            if (s == 0) {
                u16 hi, lo; splitbf(val * SCL2, hi, lo);   // pre-scaled Q
                qHi[(h * NPTS + n) * HD + hd] = hi;
                qLo[(h * NPTS + n) * HD + hd] = lo;
            } else if (s == 1) {
                u16 hi, lo; splitbf(val, hi, lo);
                kHi[(h * NPTS + n) * HD + hd] = hi;
                kLo[(h * NPTS + n) * HD + hd] = lo;
            } else {
                // tiled V^T: [h][key tile][hd][key%16]
                vt2[((size_t)(h * 256 + (n >> 4)) * 32 + hd) * 16 + (n & 15)] = f2bf(val);
            }
        }
    }
}

// ---------------------------------------------------------------------------
// Phase 3: attention. 512-thread blocks = 8 waves on one (head, 32 q-rows);
// wave w handles keys [w*512, (w+1)*512) as 32 INDEPENDENT 16-key granules
// (tiny live set, unroll 2 -> compiler pipelines loads under compute).
// Fixed-scale softmax via C-init = -64; no clip. Row sums on VALU.
// Two 16-row score tiles share all K/V fragments. LDS sum-combine, wave 0
// writes. blockIdx&7 = head -> per-XCD L2 holds one head's K/V.
// ---------------------------------------------------------------------------
__global__ __launch_bounds__(512, 4) void k_attn(
        const u16* __restrict__ qHi, const u16* __restrict__ qLo,
        const u16* __restrict__ kHi, const u16* __restrict__ kLo,
        const u16* __restrict__ vt2,
        u16* __restrict__ catH) {
    __shared__ float cmb[KSPLIT][64][19];  // {SA,o0A[4],o1A[4],SB,o0B[4],o1B[4]}
    int b = blockIdx.x;
    int h = b & 7;                        // head -> XCD affinity
    int qb = b >> 3;                      // 0..127 (32 rows each)
    int w = threadIdx.x >> 6;             // key-split index 0..7
    int l = threadIdx.x & 63, lr = l & 15, lg = l >> 4;

    size_t qoff = (size_t)(h * NPTS + qb * QROWS + lr) * HD + lg * 8;
    s8 qh0 = ld8(qHi + qoff);
    s8 ql0 = ld8(qLo + qoff);
    s8 qh1 = ld8(qHi + qoff + 16 * HD);
    s8 ql1 = ld8(qLo + qoff + 16 * HD);

    // hoisted bases (32-bit per-iter offsets)
    const u16* khb = kHi + (size_t)h * NPTS * HD + lr * HD + lg * 8;
    const u16* klb = kLo + (size_t)h * NPTS * HD + lr * HD + lg * 8;
    const u16* vtb = vt2 + (size_t)h * (NPTS / 16) * 512 + lr * 16 + lg * 4;

    const f4 cinit = {-PRESC, -PRESC, -PRESC, -PRESC};

    f4 o0A = {}, o1A = {}, o0B = {}, o1B = {};
    float psA0 = 0.0f, psA1 = 0.0f, psB0 = 0.0f, psB1 = 0.0f;

#if !HAVE_MFMA16
    u32 sA0[2], sA1[2], sB0[2], sB1[2];   // 2-granule staging for fallback
#endif

#pragma unroll 2
    for (int kt = w * KTPW; kt < (w + 1) * KTPW; ++kt) {
        int koff = kt * (16 * HD);
        s8 kh = ld8(khb + koff);
        s8 kl = ld8(klb + koff);
#if HAVE_MFMA16
        s4v v0 = *reinterpret_cast<const s4v*>(vtb + kt * 512);
        s4v v1 = *reinterpret_cast<const s4v*>(vtb + kt * 512 + 256);
#endif
        f4 a = MFMA32(kl, qh0, cinit);
        a = MFMA32(kh, ql0, a);
        a = MFMA32(kh, qh0, a);
        f4 bb = MFMA32(kl, qh1, cinit);
        bb = MFMA32(kh, ql1, bb);
        bb = MFMA32(kh, qh1, bb);
        // p' = 2^(s-64); VALU row-sum partials (2 chains per tile)
        float a0 = EXP2(a[0]),  a1 = EXP2(a[1]),  a2 = EXP2(a[2]),  a3 = EXP2(a[3]);
        float b0 = EXP2(bb[0]), b1 = EXP2(bb[1]), b2 = EXP2(bb[2]), b3 = EXP2(bb[3]);
        psA0 += a0 + a1; psA1 += a2 + a3;
        psB0 += b0 + b1; psB1 += b2 + b3;
#if HAVE_MFMA16
        union { u32 u[2]; s4v v; } puA, puB;
        puA.u[0] = bfpair(a0, a1); puA.u[1] = bfpair(a2, a3);
        puB.u[0] = bfpair(b0, b1); puB.u[1] = bfpair(b2, b3);
        o0A = MFMA16(v0, puA.v, o0A);
        o1A = MFMA16(v1, puA.v, o1A);
        o0B = MFMA16(v0, puB.v, o0B);
        o1B = MFMA16(v1, puB.v, o1B);
#else
        int par = kt & 1;
        sA0[par] = bfpair(a0, a1); sA1[par] = bfpair(a2, a3);
        sB0[par] = bfpair(b0, b1); sB1[par] = bfpair(b2, b3);
        if (par == 1) {
            int srcbase = ((lg & 1) * 2) * 16 + lr;
            bool hiQuad = (lg >> 1) != 0;
            union { u32 u[4]; s8 v; } buA, buB;
#pragma unroll
            for (int wi = 0; wi < 4; ++wi) {
                int src = srcbase + ((wi >> 1) << 4);
                u32 x0 = (u32)__shfl((int)((wi & 1) ? sA1[0] : sA0[0]), src);
                u32 x1 = (u32)__shfl((int)((wi & 1) ? sA1[1] : sA0[1]), src);
                buA.u[wi] = hiQuad ? x1 : x0;
                u32 y0 = (u32)__shfl((int)((wi & 1) ? sB1[0] : sB0[0]), src);
                u32 y1 = (u32)__shfl((int)((wi & 1) ? sB1[1] : sB0[1]), src);
                buB.u[wi] = hiQuad ? y1 : y0;
            }
            int t = (kt - 1) + (lg >> 1);
            const u16* vt = vtb - lr * 16 - lg * 4 + t * 512 + (lg & 1) * 8;
            s8 v0f = ld8(vt + lr * 16);
            s8 v1f = ld8(vt + (16 + lr) * 16);
            o0A = MFMA32(v0f, buA.v, o0A);
            o1A = MFMA32(v1f, buA.v, o1A);
            o0B = MFMA32(v0f, buB.v, o0B);
            o1B = MFMA32(v1f, buB.v, o1B);
        }
#endif
    }

    // per-wave: reduce S' across the 4 lane groups (once)
    float SA = psA0 + psA1;
    SA += __shfl_xor(SA, 16);
    SA += __shfl_xor(SA, 32);
    float SB = psB0 + psB1;
    SB += __shfl_xor(SB, 16);
    SB += __shfl_xor(SB, 32);

    // deposit per-wave partials (all share the fixed 2^-64 scale)
    float* c = cmb[w][l];
    c[0] = SA;
#pragma unroll
    for (int r = 0; r < 4; ++r) { c[1 + r] = o0A[r]; c[5 + r] = o1A[r]; }
    c[9] = SB;
#pragma unroll
    for (int r = 0; r < 4; ++r) { c[10 + r] = o0B[r]; c[14 + r] = o1B[r]; }
    __syncthreads();

    if (w == 0) {
        float StA = 0.0f, StB = 0.0f;
        f4 O0A = {}, O1A = {}, O0B = {}, O1B = {};
#pragma unroll
        for (int ww = 0; ww < KSPLIT; ++ww) {
            const float* cc = cmb[ww][l];
            StA += cc[0];
            StB += cc[9];
#pragma unroll
            for (int r = 0; r < 4; ++r) {
                O0A[r] += cc[1 + r];
                O1A[r] += cc[5 + r];
                O0B[r] += cc[10 + r];
                O1B[r] += cc[14 + r];
            }
        }
        // reference's +1e-6 on the max-normalized sum perturbs output by
        // <=1e-6 relative -- negligible vs bf16 rounding; plain divide.
        float invA = 1.0f / StA;
        float invB = 1.0f / StB;
        int n = qb * QROWS + lr;
        u16* dstA = catH + n * 256 + h * HD + lg * 4;
        *reinterpret_cast<uint2*>(dstA) =
            make_uint2(bfpair(O0A[0] * invA, O0A[1] * invA),
                       bfpair(O0A[2] * invA, O0A[3] * invA));
        *reinterpret_cast<uint2*>(dstA + 16) =
            make_uint2(bfpair(O1A[0] * invA, O1A[1] * invA),
                       bfpair(O1A[2] * invA, O1A[3] * invA));
        u16* dstB = dstA + 16 * 256;
        *reinterpret_cast<uint2*>(dstB) =
            make_uint2(bfpair(O0B[0] * invB, O0B[1] * invB),
                       bfpair(O0B[2] * invB, O0B[3] * invB));
        *reinterpret_cast<uint2*>(dstB + 16) =
            make_uint2(bfpair(O1B[0] * invB, O1B[1] * invB),
                       bfpair(O1B[2] * invB, O1B[3] * invB));
    }
}

// ---------------------------------------------------------------------------
// Phase 4: out = cat @ wo + bo + x   (bf16 MFMA, fp32 epilogue)
// ---------------------------------------------------------------------------
__global__ __launch_bounds__(256) void k_out(
        const u16* __restrict__ catH, const u16* __restrict__ woT,
        const float* __restrict__ bo, const float* __restrict__ x,
        float* __restrict__ out) {
    int w = threadIdx.x >> 6, l = threadIdx.x & 63;
    int lr = l & 15, lg = l >> 4;
    int r0 = blockIdx.x * 64 + w * 16;
    int c0 = blockIdx.y * 64;
    f4 acc[4] = {};
#pragma unroll
    for (int kk = 0; kk < 8; ++kk) {
        s8 a = ld8(catH + (r0 + lr) * 256 + kk * 32 + lg * 8);
#pragma unroll
        for (int ct = 0; ct < 4; ++ct) {
            s8 b = ld8(woT + (c0 + ct * 16 + lr) * 256 + kk * 32 + lg * 8);
            acc[ct] = MFMA32(a, b, acc[ct]);
        }
    }
#pragma unroll
    for (int ct = 0; ct < 4; ++ct) {
        int c = c0 + ct * 16 + lr;
        float bias = bo[c];
#pragma unroll
        for (int r = 0; r < 4; ++r) {
            int n = r0 + lg * 4 + r;
            out[n * 256 + c] = acc[ct][r] + bias + x[n * 256 + c];
        }
    }
}

// ---------------------------------------------------------------------------
extern "C" void kernel_launch(void* const* d_in, const int* in_sizes, int n_in,
                              void* d_out, int out_size, void* d_ws, size_t ws_size,
                              hipStream_t stream) {
    const float* x      = (const float*)d_in[0];
    const int*   coords = (const int*)d_in[1];
    const float* wq     = (const float*)d_in[2];
    const float* bq     = (const float*)d_in[3];
    const float* wk     = (const float*)d_in[4];
    const float* bk     = (const float*)d_in[5];
    const float* wv     = (const float*)d_in[6];
    const float* bv     = (const float*)d_in[7];
    const float* wo     = (const float*)d_in[8];
    const float* bo     = (const float*)d_in[9];
    float* out = (float*)d_out;

    char* ws = (char*)d_ws;
    size_t off = 0;
    auto alloc = [&](size_t bytes) {
        char* p = ws + off;
        off = (off + bytes + 255) & ~(size_t)255;
        return p;
    };
    u16* xcHi = (u16*)alloc((size_t)NPTS * DINP * 2);
    u16* xcLo = (u16*)alloc((size_t)NPTS * DINP * 2);
    u16* wtHi = (u16*)alloc((size_t)COUT * DINP * 2);
    u16* wtLo = (u16*)alloc((size_t)COUT * DINP * 2);
    u16* qHi  = (u16*)alloc((size_t)NH * NPTS * HD * 2);
    u16* qLo  = (u16*)alloc((size_t)NH * NPTS * HD * 2);
    u16* kHi  = (u16*)alloc((size_t)NH * NPTS * HD * 2);
    u16* kLo  = (u16*)alloc((size_t)NH * NPTS * HD * 2);
    u16* vt2  = (u16*)alloc((size_t)NH * NPTS * HD * 2);
    u16* catH = (u16*)alloc((size_t)NPTS * 256 * 2);
    u16* woT  = (u16*)alloc((size_t)256 * 256 * 2);
    (void)ws_size; (void)in_sizes; (void)n_in; (void)out_size;

    k_wprep<<<COUT, 64, 0, stream>>>(wq, wk, wv, wtHi, wtLo);
    k_woprep<<<256, 256, 0, stream>>>(wo, woT);
    k_featurize<<<NPTS, 64, 0, stream>>>(x, coords, xcHi, xcLo);
    k_qkv<<<dim3(NPTS / 64, COUT / 64), 256, 0, stream>>>(
        xcHi, xcLo, wtHi, wtLo, bq, bk, bv, qHi, qLo, kHi, kLo, vt2);
    k_attn<<<NPTS / QROWS * NH, 512, 0, stream>>>(qHi, qLo, kHi, kLo, vt2, catH);
    k_out<<<dim3(NPTS / 64, 256 / 64), 256, 0, stream>>>(catH, woT, bo, x, out);
}

// Round 11
// 80.711 us; speedup vs baseline: 1.1637x; 1.1629x over previous
//
#include <hip/hip_runtime.h>
#include <hip/hip_bf16.h>

// ---------------------------------------------------------------------------
// MultiHeadAttention: feats L2-norm + clamp(coords) concat -> per-head QKV
// (DIN=259, HD=32, H=8) -> softmax attention (N=4096, clip +-100, /(sum+1e-6))
// -> output proj + bias + residual.
// Precision: hi/lo bf16 split (3-MFMA fp32 emulation) for QKV proj and QK^T;
// bf16 P and bf16 V for PV; plain bf16 for output proj.
// Attention: swapped-operand QK^T (S^T = K.Q^T, log2 domain via pre-scaled Q),
// fixed-scale softmax p' = 2^(s-64) in the MFMA C-init, no clip (score bound
// 98 log2 < 144). Rounds 8-10 proved k_attn duration tracks K/V L2 traffic
// (101us @1.57GB vs 58.5us @786MB, variant-insensitive) -> QROWS=64: each
// K/V granule feeds FOUR 16-row score tiles, halving bytes/CU again.
// P->bf16 via hardware v_cvt_pk_bf16_f32 (software RNE was ~36 VALU/granule).
// Split-K 8 waves/block; 3-barrier tree combine in [4][64][37] LDS.
// ---------------------------------------------------------------------------

using s8  = __attribute__((ext_vector_type(8))) short;   // 8 x bf16 (4 VGPR)
using s4v = __attribute__((ext_vector_type(4))) short;   // 4 x bf16 (2 VGPR)
using f4  = __attribute__((ext_vector_type(4))) float;   // MFMA C/D
typedef unsigned short u16;
typedef unsigned int   u32;

#define NPTS 4096
#define NH   8
#define HD   32
#define DIN  259
#define DINP 288       // padded K-dim for QKV GEMM (9 x 32)
#define COUT 768       // 3*NH*HD, col c = s*256 + h*32 + hd (s: 0=q,1=k,2=v)
#define KSPLIT 8       // waves per block, each takes NPTS/KSPLIT keys
#define QROWS 64       // q-rows per block (four 16-row MFMA tiles)
#define NTILE 4
#define KTPW (NPTS / KSPLIT / 16)   // 16-key granules per wave = 32

// scale * log2(e): QK^T in log2 domain (monotone, identical softmax)
#define SCL2  (0.17677669529663687f * 1.4426950408889634f)
#define PRESC 64.0f    // fixed softmax prescale: p' = 2^(s - 64)

#define MFMA32(a, b, c) __builtin_amdgcn_mfma_f32_16x16x32_bf16((a), (b), (c), 0, 0, 0)

#if __has_builtin(__builtin_amdgcn_mfma_f32_16x16x16bf16_1k)
#define HAVE_MFMA16 1
#define MFMA16(a, b, c) __builtin_amdgcn_mfma_f32_16x16x16bf16_1k((a), (b), (c), 0, 0, 0)
#else
#define HAVE_MFMA16 0
#endif

#if __has_builtin(__builtin_amdgcn_exp2f)
#define EXP2(x) __builtin_amdgcn_exp2f(x)
#else
#define EXP2(x) exp2f(x)
#endif

__device__ __forceinline__ u16 f2bf(float f) {           // RNE, for prep paths
    u32 u = __float_as_uint(f);
    u32 r = u + 0x7FFFu + ((u >> 16) & 1u);
    return (u16)(r >> 16);
}
__device__ __forceinline__ float bf2f(u16 h) { return __uint_as_float(((u32)h) << 16); }
__device__ __forceinline__ void splitbf(float v, u16& hi, u16& lo) {
    hi = f2bf(v);
    lo = f2bf(v - bf2f(hi));
}
__device__ __forceinline__ s8 ld8(const u16* p) { return *reinterpret_cast<const s8*>(p); }
// hardware packed f32->bf16 (RNE): dst.lo = bf16(a), dst.hi = bf16(b)
__device__ __forceinline__ u32 cvtpk(float a, float b) {
    u32 r;
    asm("v_cvt_pk_bf16_f32 %0, %1, %2" : "=v"(r) : "v"(a), "v"(b));
    return r;
}

// ---------------------------------------------------------------------------
// Phase 0a: build transposed+split QKV weight matrix Wt[COUT][DINP]
// ---------------------------------------------------------------------------
__global__ void k_wprep(const float* __restrict__ wq, const float* __restrict__ wk,
                        const float* __restrict__ wv,
                        u16* __restrict__ wtHi, u16* __restrict__ wtLo) {
    int c = blockIdx.x;                   // 0..767
    int s = c >> 8, h = (c >> 5) & 7, hd = c & 31;
    const float* w = (s == 0) ? wq : (s == 1) ? wk : wv;
    for (int k = threadIdx.x; k < DINP; k += blockDim.x) {
        float val = (k < DIN) ? w[(h * DIN + k) * HD + hd] : 0.0f;
        u16 hi, lo; splitbf(val, hi, lo);
        wtHi[c * DINP + k] = hi;
        wtLo[c * DINP + k] = lo;
    }
}

// ---------------------------------------------------------------------------
// Phase 0b: woT[c][k] = wo[k][c] (bf16)
// ---------------------------------------------------------------------------
__global__ void k_woprep(const float* __restrict__ wo, u16* __restrict__ woT) {
    int c = blockIdx.x;
    int k = threadIdx.x;                  // blockDim = 256
    woT[c * 256 + k] = f2bf(wo[k * 256 + c]);
}

// ---------------------------------------------------------------------------
// Phase 1: featurize. One 64-lane wave per row.
// ---------------------------------------------------------------------------
__global__ __launch_bounds__(64) void k_featurize(const float* __restrict__ x,
                                                  const int* __restrict__ coords,
                                                  u16* __restrict__ xcHi,
                                                  u16* __restrict__ xcLo) {
    int row = blockIdx.x;
    int l = threadIdx.x;
    f4 v = *reinterpret_cast<const f4*>(x + row * 256 + 4 * l);
    float ss = v[0] * v[0] + v[1] * v[1] + v[2] * v[2] + v[3] * v[3];
#pragma unroll
    for (int m = 1; m < 64; m <<= 1) ss += __shfl_xor(ss, m);
    float inv = 1.0f / (sqrtf(ss) + 1e-6f);
#pragma unroll
    for (int j = 0; j < 4; ++j) {
        u16 hi, lo; splitbf(v[j] * inv, hi, lo);
        xcHi[row * DINP + 4 * l + j] = hi;
        xcLo[row * DINP + 4 * l + j] = lo;
    }
    if (l < 32) {
        int col = 256 + l;
        float val = 0.0f;
        if (col < DIN) {
            float c = (float)coords[row * 3 + (col - 256)];
            val = fminf(fmaxf(c, -100.0f), 100.0f);
        }
        u16 hi, lo; splitbf(val, hi, lo);
        xcHi[row * DINP + col] = hi;
        xcLo[row * DINP + col] = lo;
    }
}

// ---------------------------------------------------------------------------
// Phase 2: QKV GEMM  [4096 x DINP] x [DINP x 768] with 3-MFMA emulation.
// q (pre-scaled by SCL2), k row-major [h][n][hd] (hi/lo);
// v tiled [h][n>>4][hd][n&15] (bf16).
// ---------------------------------------------------------------------------
__global__ __launch_bounds__(256) void k_qkv(
        const u16* __restrict__ xcHi, const u16* __restrict__ xcLo,
        const u16* __restrict__ wtHi, const u16* __restrict__ wtLo,
        const float* __restrict__ bq, const float* __restrict__ bk,
        const float* __restrict__ bv,
        u16* __restrict__ qHi, u16* __restrict__ qLo,
        u16* __restrict__ kHi, u16* __restrict__ kLo,
        u16* __restrict__ vt2) {
    int w = threadIdx.x >> 6, l = threadIdx.x & 63;
    int lr = l & 15, lg = l >> 4;
    int r0 = blockIdx.x * 64 + w * 16;    // wave's row base
    int c0 = blockIdx.y * 64;             // block's col base

    f4 acc[4] = {};
    const u16* aH = xcHi + (r0 + lr) * DINP + lg * 8;
    const u16* aL = xcLo + (r0 + lr) * DINP + lg * 8;
#pragma unroll
    for (int kk = 0; kk < 9; ++kk) {
        s8 ah = ld8(aH + kk * 32);
        s8 al = ld8(aL + kk * 32);
#pragma unroll
        for (int ct = 0; ct < 4; ++ct) {
            int c = c0 + ct * 16 + lr;
            s8 bh = ld8(wtHi + c * DINP + kk * 32 + lg * 8);
            s8 bl = ld8(wtLo + c * DINP + kk * 32 + lg * 8);
            acc[ct] = MFMA32(al, bh, acc[ct]);
            acc[ct] = MFMA32(ah, bl, acc[ct]);
            acc[ct] = MFMA32(ah, bh, acc[ct]);
        }
    }
#pragma unroll
    for (int ct = 0; ct < 4; ++ct) {
        int c = c0 + ct * 16 + lr;
        int s = c >> 8, h = (c >> 5) & 7, hd = c & 31;
        float bias = ((s == 0) ? bq : (s == 1) ? bk : bv)[h * HD + hd];
#pragma unroll
        for (int r = 0; r < 4; ++r) {
            int n = r0 + lg * 4 + r;
            float val = acc[ct][r] + bias;
            if (s == 0) {
                u16 hi, lo; splitbf(val * SCL2, hi, lo);   // pre-scaled Q
                qHi[(h * NPTS + n) * HD + hd] = hi;
                qLo[(h * NPTS + n) * HD + hd] = lo;
            } else if (s == 1) {
                u16 hi, lo; splitbf(val, hi, lo);
                kHi[(h * NPTS + n) * HD + hd] = hi;
                kLo[(h * NPTS + n) * HD + hd] = lo;
            } else {
                // tiled V^T: [h][key tile][hd][key%16]
                vt2[((size_t)(h * 256 + (n >> 4)) * 32 + hd) * 16 + (n & 15)] = f2bf(val);
            }
        }
    }
}

// ---------------------------------------------------------------------------
// Phase 3: attention. 512-thread blocks = 8 waves on one (head, 64 q-rows);
// wave w handles keys [w*512, (w+1)*512) as 32 independent 16-key granules;
// each granule's K/V feeds FOUR 16-row score tiles (bytes/CU halved vs
// QROWS=32 -- the proven bottleneck). Fixed-scale softmax via C-init = -64;
// no clip. P->bf16 via v_cvt_pk. 3-barrier tree combine; wave 0 writes.
// blockIdx&7 = head -> per-XCD L2 holds one head's K/V.
// ---------------------------------------------------------------------------
__global__ __launch_bounds__(512, 4) void k_attn(
        const u16* __restrict__ qHi, const u16* __restrict__ qLo,
        const u16* __restrict__ kHi, const u16* __restrict__ kLo,
        const u16* __restrict__ vt2,
        u16* __restrict__ catH) {
    // per-lane payload: {S[4], o0[4][4], o1[4][4]} = 36 floats, stride 37
    __shared__ float cmb[4][64][37];
    int b = blockIdx.x;
    int h = b & 7;                        // head -> XCD affinity
    int qb = b >> 3;                      // 0..63 (64 rows each)
    int w = threadIdx.x >> 6;             // key-split index 0..7
    int l = threadIdx.x & 63, lr = l & 15, lg = l >> 4;

    size_t qoff = (size_t)(h * NPTS + qb * QROWS + lr) * HD + lg * 8;
    s8 qh[NTILE], ql[NTILE];
#pragma unroll
    for (int t = 0; t < NTILE; ++t) {
        qh[t] = ld8(qHi + qoff + t * 16 * HD);
        ql[t] = ld8(qLo + qoff + t * 16 * HD);
    }

    // hoisted bases (32-bit per-iter offsets)
    const u16* khb = kHi + (size_t)h * NPTS * HD + lr * HD + lg * 8;
    const u16* klb = kLo + (size_t)h * NPTS * HD + lr * HD + lg * 8;
    const u16* vtb = vt2 + (size_t)h * (NPTS / 16) * 512 + lr * 16 + lg * 4;

    const f4 cinit = {-PRESC, -PRESC, -PRESC, -PRESC};

    f4 o0[NTILE] = {}, o1[NTILE] = {};
    float ps0[NTILE] = {}, ps1[NTILE] = {};

#if !HAVE_MFMA16
    u32 sP0[NTILE][2], sP1[NTILE][2];     // 2-granule staging for fallback
#endif

#pragma unroll 1
    for (int kt = w * KTPW; kt < (w + 1) * KTPW; ++kt) {
        int koff = kt * (16 * HD);
        s8 kh = ld8(khb + koff);
        s8 kl = ld8(klb + koff);
#if HAVE_MFMA16
        s4v v0 = *reinterpret_cast<const s4v*>(vtb + kt * 512);
        s4v v1 = *reinterpret_cast<const s4v*>(vtb + kt * 512 + 256);
#endif
#pragma unroll
        for (int t = 0; t < NTILE; ++t) {
            f4 st = MFMA32(kl, qh[t], cinit);
            st = MFMA32(kh, ql[t], st);
            st = MFMA32(kh, qh[t], st);
            float a0 = EXP2(st[0]), a1 = EXP2(st[1]);
            float a2 = EXP2(st[2]), a3 = EXP2(st[3]);
            ps0[t] += a0 + a1;
            ps1[t] += a2 + a3;
#if HAVE_MFMA16
            union { u32 u[2]; s4v v; } pu;
            pu.u[0] = cvtpk(a0, a1);
            pu.u[1] = cvtpk(a2, a3);
            o0[t] = MFMA16(v0, pu.v, o0[t]);
            o1[t] = MFMA16(v1, pu.v, o1[t]);
#else
            sP0[t][kt & 1] = cvtpk(a0, a1);
            sP1[t][kt & 1] = cvtpk(a2, a3);
#endif
        }
#if !HAVE_MFMA16
        if (kt & 1) {
            int srcbase = ((lg & 1) * 2) * 16 + lr;
            bool hiQuad = (lg >> 1) != 0;
            int vti = (kt - 1) + (lg >> 1);
            const u16* vtp = vtb - lr * 16 - lg * 4 + vti * 512 + (lg & 1) * 8;
            s8 vA = ld8(vtp + lr * 16);
            s8 vB = ld8(vtp + (16 + lr) * 16);
#pragma unroll
            for (int t = 0; t < NTILE; ++t) {
                union { u32 u[4]; s8 v; } bu;
#pragma unroll
                for (int wi = 0; wi < 4; ++wi) {
                    int src = srcbase + ((wi >> 1) << 4);
                    u32 x0 = (u32)__shfl((int)((wi & 1) ? sP1[t][0] : sP0[t][0]), src);
                    u32 x1 = (u32)__shfl((int)((wi & 1) ? sP1[t][1] : sP0[t][1]), src);
                    bu.u[wi] = hiQuad ? x1 : x0;
                }
                o0[t] = MFMA32(vA, bu.v, o0[t]);
                o1[t] = MFMA32(vB, bu.v, o1[t]);
            }
        }
#endif
    }

    // per-wave: reduce S' across the 4 lane groups (once)
    float S[NTILE];
#pragma unroll
    for (int t = 0; t < NTILE; ++t) {
        float s = ps0[t] + ps1[t];
        s += __shfl_xor(s, 16);
        s += __shfl_xor(s, 32);
        S[t] = s;
    }

    // tree combine over the 8 key-split waves (all share the 2^-64 scale)
    auto dep = [&](int slot) {
        float* c = cmb[slot][l];
#pragma unroll
        for (int t = 0; t < NTILE; ++t) {
            c[t] = S[t];
#pragma unroll
            for (int r = 0; r < 4; ++r) {
                c[4 + t * 4 + r] = o0[t][r];
                c[20 + t * 4 + r] = o1[t][r];
            }
        }
    };
    auto acc = [&](int slot) {
        const float* c = cmb[slot][l];
#pragma unroll
        for (int t = 0; t < NTILE; ++t) {
            S[t] += c[t];
#pragma unroll
            for (int r = 0; r < 4; ++r) {
                o0[t][r] += c[4 + t * 4 + r];
                o1[t][r] += c[20 + t * 4 + r];
            }
        }
    };

    if (w >= 4) dep(w - 4);
    __syncthreads();
    if (w < 4) acc(w);
    __syncthreads();
    if (w >= 1 && w < 4) dep(w - 1);
    __syncthreads();
    if (w == 0) {
        acc(0); acc(1); acc(2);
        // reference's +1e-6 on the max-normalized sum perturbs output by
        // <=1e-6 relative -- negligible vs bf16 rounding; plain divide.
#pragma unroll
        for (int t = 0; t < NTILE; ++t) {
            float inv = 1.0f / S[t];
            int n = qb * QROWS + t * 16 + lr;
            u16* dst = catH + n * 256 + h * HD + lg * 4;
            *reinterpret_cast<uint2*>(dst) =
                make_uint2(cvtpk(o0[t][0] * inv, o0[t][1] * inv),
                           cvtpk(o0[t][2] * inv, o0[t][3] * inv));
            *reinterpret_cast<uint2*>(dst + 16) =
                make_uint2(cvtpk(o1[t][0] * inv, o1[t][1] * inv),
                           cvtpk(o1[t][2] * inv, o1[t][3] * inv));
        }
    }
}

// ---------------------------------------------------------------------------
// Phase 4: out = cat @ wo + bo + x   (bf16 MFMA, fp32 epilogue)
// ---------------------------------------------------------------------------
__global__ __launch_bounds__(256) void k_out(
        const u16* __restrict__ catH, const u16* __restrict__ woT,
        const float* __restrict__ bo, const float* __restrict__ x,
        float* __restrict__ out) {
    int w = threadIdx.x >> 6, l = threadIdx.x & 63;
    int lr = l & 15, lg = l >> 4;
    int r0 = blockIdx.x * 64 + w * 16;
    int c0 = blockIdx.y * 64;
    f4 acc[4] = {};
#pragma unroll
    for (int kk = 0; kk < 8; ++kk) {
        s8 a = ld8(catH + (r0 + lr) * 256 + kk * 32 + lg * 8);
#pragma unroll
        for (int ct = 0; ct < 4; ++ct) {
            s8 b = ld8(woT + (c0 + ct * 16 + lr) * 256 + kk * 32 + lg * 8);
            acc[ct] = MFMA32(a, b, acc[ct]);
        }
    }
#pragma unroll
    for (int ct = 0; ct < 4; ++ct) {
        int c = c0 + ct * 16 + lr;
        float bias = bo[c];
#pragma unroll
        for (int r = 0; r < 4; ++r) {
            int n = r0 + lg * 4 + r;
            out[n * 256 + c] = acc[ct][r] + bias + x[n * 256 + c];
        }
    }
}

// ---------------------------------------------------------------------------
extern "C" void kernel_launch(void* const* d_in, const int* in_sizes, int n_in,
                              void* d_out, int out_size, void* d_ws, size_t ws_size,
                              hipStream_t stream) {
    const float* x      = (const float*)d_in[0];
    const int*   coords = (const int*)d_in[1];
    const float* wq     = (const float*)d_in[2];
    const float* bq     = (const float*)d_in[3];
    const float* wk     = (const float*)d_in[4];
    const float* bk     = (const float*)d_in[5];
    const float* wv     = (const float*)d_in[6];
    const float* bv     = (const float*)d_in[7];
    const float* wo     = (const float*)d_in[8];
    const float* bo     = (const float*)d_in[9];
    float* out = (float*)d_out;

    char* ws = (char*)d_ws;
    size_t off = 0;
    auto alloc = [&](size_t bytes) {
        char* p = ws + off;
        off = (off + bytes + 255) & ~(size_t)255;
        return p;
    };
    u16* xcHi = (u16*)alloc((size_t)NPTS * DINP * 2);
    u16* xcLo = (u16*)alloc((size_t)NPTS * DINP * 2);
    u16* wtHi = (u16*)alloc((size_t)COUT * DINP * 2);
    u16* wtLo = (u16*)alloc((size_t)COUT * DINP * 2);
    u16* qHi  = (u16*)alloc((size_t)NH * NPTS * HD * 2);
    u16* qLo  = (u16*)alloc((size_t)NH * NPTS * HD * 2);
    u16* kHi  = (u16*)alloc((size_t)NH * NPTS * HD * 2);
    u16* kLo  = (u16*)alloc((size_t)NH * NPTS * HD * 2);
    u16* vt2  = (u16*)alloc((size_t)NH * NPTS * HD * 2);
    u16* catH = (u16*)alloc((size_t)NPTS * 256 * 2);
    u16* woT  = (u16*)alloc((size_t)256 * 256 * 2);
    (void)ws_size; (void)in_sizes; (void)n_in; (void)out_size;

    k_wprep<<<COUT, 64, 0, stream>>>(wq, wk, wv, wtHi, wtLo);
    k_woprep<<<256, 256, 0, stream>>>(wo, woT);
    k_featurize<<<NPTS, 64, 0, stream>>>(x, coords, xcHi, xcLo);
    k_qkv<<<dim3(NPTS / 64, COUT / 64), 256, 0, stream>>>(
        xcHi, xcLo, wtHi, wtLo, bq, bk, bv, qHi, qLo, kHi, kLo, vt2);
    k_attn<<<NPTS / QROWS * NH, 512, 0, stream>>>(qHi, qLo, kHi, kLo, vt2, catH);
    k_out<<<dim3(NPTS / 64, 256 / 64), 256, 0, stream>>>(catH, woT, bo, x, out);
}